// Round 12
// baseline (19459.479 us; speedup 1.0000x reference)
//
#include <hip/hip_runtime.h>
#include <math.h>

// Problem constants
#define B_ 256
#define S_ 128
#define F_ 128
#define H_ 512
#define A_ 512
#define C_ 128
#define HSLICE (H_ * B_)   // 131072 floats per h slice

#define DOT4(va, vb) ((va).x*(vb).x + (va).y*(vb).y + (va).z*(vb).z + (va).w*(vb).w)

// ---------------------------------------------------------------------------
// coherence helpers: sc1 only for TINY traffic (flags, hw2 row, preds)
// ---------------------------------------------------------------------------
__device__ __forceinline__ void stf(float* p, float v) {
    __hip_atomic_store(p, v, __ATOMIC_RELAXED, __HIP_MEMORY_SCOPE_AGENT);
}
__device__ __forceinline__ float ldf_sc(const float* p) {
    return __hip_atomic_load(p, __ATOMIC_RELAXED, __HIP_MEMORY_SCOPE_AGENT);
}

// own-slot epoch barrier over a 64-block group; caller __syncthreads() after
__device__ __forceinline__ void group_wait(const int* __restrict__ flags,
                                           int gbase, int tid, int target)
{
    if (tid < 64) {
        while (true) {
            int vq = __hip_atomic_load(&flags[(gbase + tid) * 32],
                                       __ATOMIC_RELAXED,
                                       __HIP_MEMORY_SCOPE_AGENT);
            if (__all(vq >= target)) break;
            __builtin_amdgcn_s_sleep(2);
        }
    }
}

// ---------------------------------------------------------------------------
// deep-prefetch k-major dot (cached loads): 32-float double-buffer window.
// acc slots 0..3 = r0,r1,z0,z1 ; acc[NH],acc[NH+1] = n0,n1 partial.
// ---------------------------------------------------------------------------
template<int NH>
__device__ __forceinline__ void acc_chunks(const float* __restrict__ src,
                                           const float* __restrict__ W6k,
                                           int nk, int b, float* __restrict__ acc)
{
    float a0[32], a1[32];
#pragma unroll
    for (int j = 0; j < 32; ++j) a0[j] = src[(size_t)j * B_ + b];
    for (int kc = 0; kc < nk; kc += 32) {
        if (kc + 32 < nk) {
#pragma unroll
            for (int j = 0; j < 32; ++j)
                a1[j] = src[(size_t)(kc + 32 + j) * B_ + b];
        }
        const float* Wr = W6k + (size_t)kc * 6;
#pragma unroll
        for (int j = 0; j < 32; ++j) {
            float av = a0[j];
            acc[0]    = fmaf(av, Wr[j * 6 + 0], acc[0]);
            acc[1]    = fmaf(av, Wr[j * 6 + 1], acc[1]);
            acc[2]    = fmaf(av, Wr[j * 6 + 2], acc[2]);
            acc[3]    = fmaf(av, Wr[j * 6 + 3], acc[3]);
            acc[NH]   = fmaf(av, Wr[j * 6 + 4], acc[NH]);
            acc[NH+1] = fmaf(av, Wr[j * 6 + 5], acc[NH + 1]);
        }
#pragma unroll
        for (int j = 0; j < 32; ++j) a0[j] = a1[j];
    }
}

// per-lane x-row (128 k, contiguous) against W6 x-part; n -> slots 4,5
__device__ __forceinline__ void acc_xrow(const float4* __restrict__ xr,
                                         const float* __restrict__ W6k,
                                         float* __restrict__ acc)
{
    float4 c0[8], c1[8];
#pragma unroll
    for (int j = 0; j < 8; ++j) c0[j] = xr[j];
    for (int q = 0; q < 32; q += 8) {
        if (q + 8 < 32) {
#pragma unroll
            for (int j = 0; j < 8; ++j) c1[j] = xr[q + 8 + j];
        }
#pragma unroll
        for (int j = 0; j < 8; ++j) {
            const float* Wr = W6k + (size_t)((q + j) * 4) * 6;
            float e0 = c0[j].x, e1 = c0[j].y, e2 = c0[j].z, e3 = c0[j].w;
#pragma unroll
            for (int t2 = 0; t2 < 4; ++t2) {
                float av = (t2 == 0) ? e0 : (t2 == 1) ? e1 : (t2 == 2) ? e2 : e3;
                acc[0] = fmaf(av, Wr[t2 * 6 + 0], acc[0]);
                acc[1] = fmaf(av, Wr[t2 * 6 + 1], acc[1]);
                acc[2] = fmaf(av, Wr[t2 * 6 + 2], acc[2]);
                acc[3] = fmaf(av, Wr[t2 * 6 + 3], acc[3]);
                acc[4] = fmaf(av, Wr[t2 * 6 + 4], acc[4]);
                acc[5] = fmaf(av, Wr[t2 * 6 + 5], acc[5]);
            }
        }
#pragma unroll
        for (int j = 0; j < 8; ++j) c0[j] = c1[j];
    }
}

// ---------------------------------------------------------------------------
// prep kernels (unchanged)
// ---------------------------------------------------------------------------
__global__ __launch_bounds__(256)
void transpose_x(const float* __restrict__ x, float* __restrict__ xT)
{
    const int t = blockIdx.x >> 2;
    const int f0 = (blockIdx.x & 3) * 32;
    const int b = threadIdx.x;
#pragma unroll 4
    for (int ff = 0; ff < 32; ++ff) {
        int f = f0 + ff;
        xT[(size_t)t * (F_ * B_) + (size_t)f * B_ + b] =
            x[(size_t)b * (S_ * F_) + (size_t)t * F_ + f];
    }
}

__global__ __launch_bounds__(256)
void prep_w6(const float* __restrict__ Wih, const float* __restrict__ Whh,
             float* __restrict__ W6, const float* __restrict__ csrc,
             float* __restrict__ cdst, int cn)
{
    int id = blockIdx.x * 256 + threadIdx.x;
    if (csrc && id < cn) cdst[id] = csrc[id];
    if (id >= 256 * 640 * 6) return;
    int up = id / 3840;
    int rem = id - up * 3840;
    int k = rem / 6, g = rem - k * 6;
    int row = (g >> 1) * H_ + up * 2 + (g & 1);
    float val;
    if (k < F_) val = Wih[(size_t)row * F_ + k];
    else        val = Whh[(size_t)row * H_ + (k - F_)];
    W6[id] = val;
}

__global__ __launch_bounds__(256)
void prep_bias(const float* __restrict__ ebih, const float* __restrict__ ebhh,
               const float* __restrict__ dbih, const float* __restrict__ dbhh,
               float* __restrict__ bias4e, float* __restrict__ bias4d,
               float* __restrict__ h0T, int* __restrict__ eflags,
               int* __restrict__ dflags)
{
    int id = blockIdx.x * 256 + threadIdx.x;
    if (id < H_ * B_) h0T[id] = 0.f;
    if (id < 256 * 32) { eflags[id] = 0; dflags[id] = 0; }
    if (id < H_) {
        bias4e[id * 4 + 0] = ebih[id] + ebhh[id];
        bias4e[id * 4 + 1] = ebih[H_ + id] + ebhh[H_ + id];
        bias4e[id * 4 + 2] = ebih[2 * H_ + id];
        bias4e[id * 4 + 3] = ebhh[2 * H_ + id];
        bias4d[id * 4 + 0] = dbih[id] + dbhh[id];
        bias4d[id * 4 + 1] = dbih[H_ + id] + dbhh[H_ + id];
        bias4d[id * 4 + 2] = dbih[2 * H_ + id];
        bias4d[id * 4 + 3] = dbhh[2 * H_ + id];
    }
}

// ---------------------------------------------------------------------------
// PERSISTENT encoder (unchanged — validated at ~2.6 ms)
// ---------------------------------------------------------------------------
__global__ __launch_bounds__(512)
void enc_persist(const float* __restrict__ xT,
                 const float* __restrict__ W6,
                 const float* __restrict__ bias4,
                 const float* __restrict__ h0T,
                 float* __restrict__ encT,
                 int* __restrict__ eflags)
{
    __shared__ float accL[4][64][6];
    const int tid = threadIdx.x;
    const int lane = tid & 63;
    const int w = tid >> 6;
    const int kw = w >> 2;
    const int uq = w & 3;
    const int bid = blockIdx.x;
    const int jb = bid & 63;
    const int bt = bid >> 6;
    const int gbase = bt * 64;
    const int b = bt * 64 + lane;
    const int up = jb * 4 + uq;
    const float* Wb = W6 + (size_t)up * 3840;
    const int u0 = up * 2, u1 = u0 + 1;
    const float4 bb0 = *(const float4*)(bias4 + u0 * 4);
    const float4 bb1 = *(const float4*)(bias4 + u1 * 4);

    for (int t = 0; t < S_; ++t) {
        const float* inT = xT + (size_t)t * (F_ * B_);
        const float* hin = (t == 0) ? h0T : encT + (size_t)(t - 1) * HSLICE;
        float* hout = encT + (size_t)t * HSLICE;

        float acc[8];
#pragma unroll
        for (int g = 0; g < 8; ++g) acc[g] = 0.f;

        if (kw == 0) acc_chunks<4>(inT, Wb, F_, b, acc);

        if (t > 0) group_wait(eflags, gbase, tid, t);
        __syncthreads();

        float hold0 = 0.f, hold1 = 0.f;
        if (kw == 0) {
            hold0 = hin[(size_t)u0 * B_ + b];
            hold1 = hin[(size_t)u1 * B_ + b];
            acc_chunks<6>(hin, Wb + F_ * 6, 192, b, acc);
        } else {
            acc_chunks<6>(hin + (size_t)192 * B_, Wb + 320 * 6, 320, b, acc);
        }

        if (kw == 1) {
            accL[uq][lane][0] = acc[0]; accL[uq][lane][1] = acc[1];
            accL[uq][lane][2] = acc[2]; accL[uq][lane][3] = acc[3];
            accL[uq][lane][4] = acc[6]; accL[uq][lane][5] = acc[7];
        }
        __syncthreads();
        if (kw == 0) {
            float rr0 = 1.f / (1.f + expf(-(acc[0] + accL[uq][lane][0] + bb0.x)));
            float rr1 = 1.f / (1.f + expf(-(acc[1] + accL[uq][lane][1] + bb1.x)));
            float zz0 = 1.f / (1.f + expf(-(acc[2] + accL[uq][lane][2] + bb0.y)));
            float zz1 = 1.f / (1.f + expf(-(acc[3] + accL[uq][lane][3] + bb1.y)));
            float hn0 = acc[6] + accL[uq][lane][4] + bb0.w;
            float hn1 = acc[7] + accL[uq][lane][5] + bb1.w;
            float nn0 = tanhf(acc[4] + bb0.z + rr0 * hn0);
            float nn1 = tanhf(acc[5] + bb1.z + rr1 * hn1);
            stf(&hout[(size_t)u0 * B_ + b], (1.f - zz0) * nn0 + zz0 * hold0);
            stf(&hout[(size_t)u1 * B_ + b], (1.f - zz1) * nn1 + zz1 * hold1);
        }
        asm volatile("s_waitcnt vmcnt(0)" ::: "memory");
        __syncthreads();
        if (tid == 0)
            __hip_atomic_store(&eflags[bid * 32], t + 1,
                               __ATOMIC_RELAXED, __HIP_MEMORY_SCOPE_AGENT);
    }
}

// ---------------------------------------------------------------------------
// PERSISTENT decoder v3: h-ring published with NORMAL stores + agent release
// fence (L2 write-back combining; only this step's dirty lines flushed to
// MALL). Virgin cached reads. sc1 only for hw2 row / predRing / flags.
// Epochs: 3st+1 = h(st+1), 3st+2 = hw2, 3st+3 = pred.
// ---------------------------------------------------------------------------
__global__ __launch_bounds__(512)
void dec_persist(const float* __restrict__ x,       // [B][S][F]
                 const int*   __restrict__ y,       // [B][C]
                 const float* __restrict__ W6,      // [256][640][6]
                 const float* __restrict__ bias4,   // [512][4]
                 const float* __restrict__ w2,      // [A][H]
                 const float* __restrict__ v,       // [A]
                 const float* __restrict__ proj,    // [B][S][A]
                 float* __restrict__ ring,          // [128][H][B]; slice0 = h_init
                 float* __restrict__ hLast,         // [H][B]
                 float* __restrict__ hw2,           // [B][A]
                 int* __restrict__ predRing,        // [C][B]
                 float* __restrict__ nlogp, float* __restrict__ preds,
                 int* __restrict__ dflags)          // [256*32]
{
    __shared__ float accL[4][64][6];   // phase-1 reduce; reused by phase 2
    __shared__ float sh[512];
    __shared__ float sScore[S_], sProb[S_];

    const int tid = threadIdx.x;
    const int lane = tid & 63;
    const int w = tid >> 6;
    const int kw = w >> 2;
    const int uq = w & 3;
    const int bid = blockIdx.x;
    const int bt = bid >> 6;
    const int gbase = bt * 64;
    const int b = bt * 64 + lane;
    const int up = (bid & 63) * 4 + uq;
    const float* Wb = W6 + (size_t)up * 3840;
    const int u0 = up * 2, u1 = u0 + 1;
    const float4 bb0 = *(const float4*)(bias4 + u0 * 4);
    const float4 bb1 = *(const float4*)(bias4 + u1 * 4);
    const float4 v0r = *(const float4*)(v + lane * 8);
    const float4 v1r = *(const float4*)(v + lane * 8 + 4);
    // phase-2 constants
    const int aq2 = __builtin_amdgcn_readfirstlane(w & 3);
    const int kh2 = __builtin_amdgcn_readfirstlane(w >> 2);
    const int a0p = (bid & 63) * 8 + aq2 * 2;
    const float* w2r0 = w2 + (size_t)a0p * H_ + kh2 * 256;
    const float* w2r1 = w2r0 + H_;
    float* accF = (float*)accL;

    for (int st = 0; st < C_; ++st) {
        const float* hin = ring + (size_t)st * HSLICE;
        float* hout = (st < C_ - 1) ? ring + (size_t)(st + 1) * HSLICE : hLast;

        // ================ phase 1: GRU ================
        if (st > 0) { group_wait(dflags, gbase, tid, 3 * st - 2); }
        __syncthreads();
        {
            float acc[8];
#pragma unroll
            for (int g = 0; g < 8; ++g) acc[g] = 0.f;

            float hold0 = 0.f, hold1 = 0.f;
            if (kw == 0) {
                hold0 = hin[(size_t)u0 * B_ + b];
                hold1 = hin[(size_t)u1 * B_ + b];
                acc_chunks<6>(hin, Wb + F_ * 6, 192, b, acc);
            } else {
                acc_chunks<6>(hin + (size_t)192 * B_, Wb + 320 * 6, 320, b, acc);
            }

            if (st > 0) {
                group_wait(dflags, gbase, tid, 3 * st);   // pred(st-1) ready
                __syncthreads();
                if (kw == 0) {
                    int pb = __hip_atomic_load(&predRing[(st - 1) * B_ + b],
                                               __ATOMIC_RELAXED,
                                               __HIP_MEMORY_SCOPE_AGENT);
                    const float4* xr =
                        (const float4*)(x + ((size_t)b * S_ + pb) * F_);
                    acc_xrow(xr, Wb, acc);
                }
            }

            if (kw == 1) {
                accL[uq][lane][0] = acc[0]; accL[uq][lane][1] = acc[1];
                accL[uq][lane][2] = acc[2]; accL[uq][lane][3] = acc[3];
                accL[uq][lane][4] = acc[6]; accL[uq][lane][5] = acc[7];
            }
            __syncthreads();
            if (kw == 0) {
                float rr0 = 1.f / (1.f + expf(-(acc[0] + accL[uq][lane][0] + bb0.x)));
                float rr1 = 1.f / (1.f + expf(-(acc[1] + accL[uq][lane][1] + bb1.x)));
                float zz0 = 1.f / (1.f + expf(-(acc[2] + accL[uq][lane][2] + bb0.y)));
                float zz1 = 1.f / (1.f + expf(-(acc[3] + accL[uq][lane][3] + bb1.y)));
                float hn0 = acc[6] + accL[uq][lane][4] + bb0.w;
                float hn1 = acc[7] + accL[uq][lane][5] + bb1.w;
                float nn0 = tanhf(acc[4] + bb0.z + rr0 * hn0);
                float nn1 = tanhf(acc[5] + bb1.z + rr1 * hn1);
                // NORMAL cached stores (write-back, combined in L2)
                hout[(size_t)u0 * B_ + b] = (1.f - zz0) * nn0 + zz0 * hold0;
                hout[(size_t)u1 * B_ + b] = (1.f - zz1) * nn1 + zz1 * hold1;
            }
            // release: flush this step's dirty lines to the coherent point
            __builtin_amdgcn_fence(__ATOMIC_RELEASE, "agent");
            __syncthreads();
            if (tid == 0)
                __hip_atomic_store(&dflags[bid * 32], 3 * st + 1,
                                   __ATOMIC_RELAXED, __HIP_MEMORY_SCOPE_AGENT);
        }

        // ================ phase 2: hw2 GEMM slice ================
        group_wait(dflags, gbase, tid, 3 * st + 1);
        __syncthreads();
        {
            const float* hsrc = hout + (size_t)(kh2 * 256) * B_;
            float s0 = 0.f, s1 = 0.f;
            float c0[32], c1[32];
#pragma unroll
            for (int j = 0; j < 32; ++j) c0[j] = hsrc[(size_t)j * B_ + b];
            for (int kc = 0; kc < 256; kc += 32) {
                if (kc + 32 < 256) {
#pragma unroll
                    for (int j = 0; j < 32; ++j)
                        c1[j] = hsrc[(size_t)(kc + 32 + j) * B_ + b];
                }
#pragma unroll
                for (int j = 0; j < 32; ++j) {
                    s0 = fmaf(c0[j], w2r0[kc + j], s0);
                    s1 = fmaf(c0[j], w2r1[kc + j], s1);
                }
#pragma unroll
                for (int j = 0; j < 32; ++j) c0[j] = c1[j];
            }
            if (kh2 == 1) {
                accF[(aq2 * 64 + lane) * 2 + 0] = s0;
                accF[(aq2 * 64 + lane) * 2 + 1] = s1;
            }
            __syncthreads();
            if (kh2 == 0) {
                float t0 = s0 + accF[(aq2 * 64 + lane) * 2 + 0];
                float t1 = s1 + accF[(aq2 * 64 + lane) * 2 + 1];
                stf(&hw2[(size_t)b * A_ + a0p + 0], t0);   // tiny sc1 traffic
                stf(&hw2[(size_t)b * A_ + a0p + 1], t1);
            }
            asm volatile("s_waitcnt vmcnt(0)" ::: "memory");
            __syncthreads();
            if (tid == 0)
                __hip_atomic_store(&dflags[bid * 32], 3 * st + 2,
                                   __ATOMIC_RELAXED, __HIP_MEMORY_SCOPE_AGENT);
        }

        // ================ phase 3: attention (block = batch bb) ================
        group_wait(dflags, gbase, tid, 3 * st + 2);
        __syncthreads();
        {
            const int bb = bid;
            sh[tid] = ldf_sc(&hw2[(size_t)bb * A_ + tid]);  // coalesced sc1 row
            __syncthreads();

            const float* epb = proj + (size_t)bb * (S_ * A_);
            float4 q0 = *(const float4*)&sh[lane * 8];
            float4 q1 = *(const float4*)&sh[lane * 8 + 4];
            for (int si = 0; si < 16; ++si) {
                int ss = si * 8 + w;
                const float* row = epb + (size_t)ss * A_ + lane * 8;
                float4 p0 = *(const float4*)(row);
                float4 p1 = *(const float4*)(row + 4);
                float acc = fmaxf(p0.x + q0.x, 0.f) * v0r.x
                          + fmaxf(p0.y + q0.y, 0.f) * v0r.y
                          + fmaxf(p0.z + q0.z, 0.f) * v0r.z
                          + fmaxf(p0.w + q0.w, 0.f) * v0r.w
                          + fmaxf(p1.x + q1.x, 0.f) * v1r.x
                          + fmaxf(p1.y + q1.y, 0.f) * v1r.y
                          + fmaxf(p1.z + q1.z, 0.f) * v1r.z
                          + fmaxf(p1.w + q1.w, 0.f) * v1r.w;
#pragma unroll
                for (int off = 32; off; off >>= 1) acc += __shfl_down(acc, off);
                if (lane == 0) sScore[ss] = acc;
            }
            __syncthreads();

            if (tid < 64) {
                float s0v = sScore[tid], s1v = sScore[tid + 64];
                float m = fmaxf(s0v, s1v);
#pragma unroll
                for (int off = 32; off; off >>= 1) m = fmaxf(m, __shfl_xor(m, off));
                float e0 = expf(s0v - m), e1 = expf(s1v - m);
                float se = e0 + e1;
#pragma unroll
                for (int off = 32; off; off >>= 1) se += __shfl_xor(se, off);
                float p0 = e0 / se, p1 = e1 / se;
                sProb[tid] = p0; sProb[tid + 64] = p1;
                float pm = fmaxf(p0, p1);
#pragma unroll
                for (int off = 32; off; off >>= 1) pm = fmaxf(pm, __shfl_xor(pm, off));
                float t0 = expf(p0 - pm), t1 = expf(p1 - pm);
                float T = t0 + t1;
#pragma unroll
                for (int off = 32; off; off >>= 1) T += __shfl_xor(T, off);
                float bv = p0; int bi2 = tid;
                if (p1 > bv) { bv = p1; bi2 = tid + 64; }
#pragma unroll
                for (int off = 32; off; off >>= 1) {
                    float ov = __shfl_xor(bv, off);
                    int oi = __shfl_xor(bi2, off);
                    if (ov > bv || (ov == bv && oi < bi2)) { bv = ov; bi2 = oi; }
                }
                if (tid == 0) {
                    int yy = y[(size_t)bb * C_ + st];
                    float py = sProb[yy];
                    nlogp[(size_t)st * B_ + bb] = -(py - pm - logf(T));
                    preds[(size_t)bb * C_ + st] = (float)bi2;
                    __hip_atomic_store(&predRing[st * B_ + bb], bi2,
                                       __ATOMIC_RELAXED, __HIP_MEMORY_SCOPE_AGENT);
                }
            }
            asm volatile("s_waitcnt vmcnt(0)" ::: "memory");
            __syncthreads();
            if (tid == 0)
                __hip_atomic_store(&dflags[bid * 32], 3 * st + 3,
                                   __ATOMIC_RELAXED, __HIP_MEMORY_SCOPE_AGENT);
        }
    }
}

// ---------------------------------------------------------------------------
// proj[b][s][a] = sum_j encT[s][j][b] * w1[a][j]
// ---------------------------------------------------------------------------
__global__ __launch_bounds__(256)
void proj_gemm(const float* __restrict__ encT, const float* __restrict__ w1,
               float* __restrict__ proj)
{
    __shared__ float sA[32][128];
    __shared__ float sB[32][128];
    const int tid = threadIdx.x;
    const int s = blockIdx.z;
    const int b0 = blockIdx.y * 128;
    const int a0 = blockIdx.x * 128;
    const int tx = tid & 15, ty = tid >> 4;

    float acc[8][8];
#pragma unroll
    for (int i = 0; i < 8; ++i)
#pragma unroll
        for (int j = 0; j < 8; ++j) acc[i][j] = 0.f;

    const float* Abase = encT + (size_t)s * HSLICE + b0;
    for (int kc = 0; kc < H_; kc += 32) {
#pragma unroll
        for (int p = 0; p < 16; ++p) {
            int idx = tid + p * 256;
            int kj = idx >> 7, bbb = idx & 127;
            sA[kj][bbb] = Abase[(size_t)(kc + kj) * B_ + bbb];
        }
#pragma unroll
        for (int p = 0; p < 16; ++p) {
            int idx = tid + p * 256;
            int aa = idx >> 5, kj = idx & 31;
            sB[kj][aa] = w1[(size_t)(a0 + aa) * H_ + kc + kj];
        }
        __syncthreads();
#pragma unroll
        for (int kj = 0; kj < 32; ++kj) {
            float4 af0 = *(const float4*)&sA[kj][ty * 8];
            float4 af1 = *(const float4*)&sA[kj][ty * 8 + 4];
            float4 bf0 = *(const float4*)&sB[kj][tx * 8];
            float4 bf1 = *(const float4*)&sB[kj][tx * 8 + 4];
            float am[8] = {af0.x, af0.y, af0.z, af0.w, af1.x, af1.y, af1.z, af1.w};
            float bn[8] = {bf0.x, bf0.y, bf0.z, bf0.w, bf1.x, bf1.y, bf1.z, bf1.w};
#pragma unroll
            for (int i = 0; i < 8; ++i)
#pragma unroll
                for (int j = 0; j < 8; ++j)
                    acc[i][j] = fmaf(am[i], bn[j], acc[i][j]);
        }
        __syncthreads();
    }
#pragma unroll
    for (int i = 0; i < 8; ++i) {
        float* dst = proj + ((size_t)(b0 + ty * 8 + i) * S_ + s) * A_ + a0 + tx * 8;
        *(float4*)(dst) = make_float4(acc[i][0], acc[i][1], acc[i][2], acc[i][3]);
        *(float4*)(dst + 4) = make_float4(acc[i][4], acc[i][5], acc[i][6], acc[i][7]);
    }
}

__global__ void final_loss(const float* __restrict__ nlogp, float* __restrict__ out)
{
    __shared__ float part[C_];
    const int i = threadIdx.x; // 128
    float s = 0.f;
    for (int b = 0; b < B_; ++b) s += nlogp[(size_t)i * B_ + b];
    part[i] = s / (float)B_;
    __syncthreads();
    if (i == 0) {
        float t = 0.f;
        for (int k = 0; k < C_; ++k) t += part[k];
        out[0] = t / (float)B_ / (float)C_;
    }
}

extern "C" void kernel_launch(void* const* d_in, const int* in_sizes, int n_in,
                              void* d_out, int out_size, void* d_ws, size_t ws_size,
                              hipStream_t stream)
{
    (void)in_sizes; (void)n_in; (void)out_size; (void)ws_size;
    const float* x    = (const float*)d_in[0];
    const int*   y    = (const int*)d_in[1];
    const float* eWih = (const float*)d_in[2];
    const float* eWhh = (const float*)d_in[3];
    const float* ebih = (const float*)d_in[4];
    const float* ebhh = (const float*)d_in[5];
    const float* dWih = (const float*)d_in[6];
    const float* dWhh = (const float*)d_in[7];
    const float* dbih = (const float*)d_in[8];
    const float* dbhh = (const float*)d_in[9];
    const float* w1   = (const float*)d_in[10];
    const float* w2   = (const float*)d_in[11];
    const float* v    = (const float*)d_in[12];
    float* out = (float*)d_out;

    float* ws = (float*)d_ws;
    // Region A [0, 16,777,216): encT during encode; h-ring[128] during decode.
    float* encT    = ws;
    float* ring    = ws;
    float* encT127 = ws + (size_t)127 * HSLICE;
    // Region B [16,777,216, 33,554,432): proj. Pre-proj: xT, W6e, h0T.
    float* projB  = ws + 16777216;
    float* xT     = projB;                    // 4,194,304
    float* W6e    = projB + 4194304;          // 983,040
    float* h0T    = projB + 5177344;          // 131,072
    // Region C beyond 33,554,432:
    float* C0     = ws + 33554432;
    float* bias4e = C0;                       // 2048
    float* bias4d = C0 + 2048;                // 2048
    float* nlogp  = C0 + 4096;                // 32,768
    float* hLast  = C0 + 36864;               // 131,072
    float* hw2    = C0 + 167936;              // 131,072
    float* W6d    = C0 + 430080;              // 983,040
    int*   eflags   = (int*)(C0 + 1413120);   // 8192 ints
    int*   dflags   = eflags + 8192;          // 8192 ints
    int*   predRing = dflags + 8192;          // 32,768 ints

    // ---- prep ----
    prep_bias<<<dim3(512), 256, 0, stream>>>(ebih, ebhh, dbih, dbhh,
                                             bias4e, bias4d, h0T, eflags, dflags);
    transpose_x<<<dim3(512), 256, 0, stream>>>(x, xT);
    prep_w6<<<dim3(3840), 256, 0, stream>>>(eWih, eWhh, W6e,
                                            (const float*)nullptr,
                                            (float*)nullptr, 0);

    // ---- encoder: ONE persistent kernel ----
    {
        void* a[] = { (void*)&xT, (void*)&W6e, (void*)&bias4e, (void*)&h0T,
                      (void*)&encT, (void*)&eflags };
        hipLaunchCooperativeKernel((const void*)enc_persist,
                                   dim3(256), dim3(512), a, 0, stream);
    }

    // ---- proj (reads all encT) ----
    proj_gemm<<<dim3(4, 2, 128), 256, 0, stream>>>(encT, w1, projB);

    // ---- decoder prep: W6d (region C) + copy h_init -> ring[0] ----
    prep_w6<<<dim3(3840), 256, 0, stream>>>(dWih, dWhh, W6d,
                                            encT127, ring, HSLICE);

    // ---- decoder: ONE persistent kernel ----
    {
        void* a[] = { (void*)&x, (void*)&y, (void*)&W6d, (void*)&bias4d,
                      (void*)&w2, (void*)&v, (void*)&projB, (void*)&ring,
                      (void*)&hLast, (void*)&hw2, (void*)&predRing,
                      (void*)&nlogp, (void*)&out, (void*)&dflags };
        hipLaunchCooperativeKernel((const void*)dec_persist,
                                   dim3(256), dim3(512), a, 0, stream);
    }

    final_loss<<<dim3(1), 128, 0, stream>>>(nlogp, out + (size_t)B_ * C_);
}

// Round 13
// 15436.755 us; speedup vs baseline: 1.2606x; 1.2606x over previous
//
#include <hip/hip_runtime.h>
#include <math.h>

// Problem constants
#define B_ 256
#define S_ 128
#define F_ 128
#define H_ 512
#define A_ 512
#define C_ 128
#define HSLICE (H_ * B_)   // 131072 floats per h slice

#define DOT4(va, vb) ((va).x*(vb).x + (va).y*(vb).y + (va).z*(vb).z + (va).w*(vb).w)

// ---------------------------------------------------------------------------
// coherence helpers: sc1 publish stores (small traffic only), packed flags
// ---------------------------------------------------------------------------
__device__ __forceinline__ void stf(float* p, float v) {
    __hip_atomic_store(p, v, __ATOMIC_RELAXED, __HIP_MEMORY_SCOPE_AGENT);
}
__device__ __forceinline__ void sti(int* p, int v) {
    __hip_atomic_store(p, v, __ATOMIC_RELAXED, __HIP_MEMORY_SCOPE_AGENT);
}
__device__ __forceinline__ float ldf_sc(const float* p) {
    return __hip_atomic_load(p, __ATOMIC_RELAXED, __HIP_MEMORY_SCOPE_AGENT);
}

// Packed own-slot epoch barrier over a 64-block group: the group's 64 flags
// span 4 cache lines -> poll cost 4 lines instead of 64. s_sleep(4) backoff.
// Caller must __syncthreads() after.
__device__ __forceinline__ void group_wait(const int* __restrict__ flags,
                                           int gbase, int tid, int target)
{
    if (tid < 64) {
        while (true) {
            int vq = __hip_atomic_load(&flags[gbase + tid],
                                       __ATOMIC_RELAXED,
                                       __HIP_MEMORY_SCOPE_AGENT);
            if (__all(vq >= target)) break;
            __builtin_amdgcn_s_sleep(4);
        }
    }
}

// ---------------------------------------------------------------------------
// deep-prefetch k-major dot (cached loads): 32-float double-buffer window.
// acc slots 0..3 = r0,r1,z0,z1 ; acc[NH],acc[NH+1] = n0,n1 partial.
// ---------------------------------------------------------------------------
template<int NH>
__device__ __forceinline__ void acc_chunks(const float* __restrict__ src,
                                           const float* __restrict__ W6k,
                                           int nk, int b, float* __restrict__ acc)
{
    float a0[32], a1[32];
#pragma unroll
    for (int j = 0; j < 32; ++j) a0[j] = src[(size_t)j * B_ + b];
    for (int kc = 0; kc < nk; kc += 32) {
        if (kc + 32 < nk) {
#pragma unroll
            for (int j = 0; j < 32; ++j)
                a1[j] = src[(size_t)(kc + 32 + j) * B_ + b];
        }
        const float* Wr = W6k + (size_t)kc * 6;
#pragma unroll
        for (int j = 0; j < 32; ++j) {
            float av = a0[j];
            acc[0]    = fmaf(av, Wr[j * 6 + 0], acc[0]);
            acc[1]    = fmaf(av, Wr[j * 6 + 1], acc[1]);
            acc[2]    = fmaf(av, Wr[j * 6 + 2], acc[2]);
            acc[3]    = fmaf(av, Wr[j * 6 + 3], acc[3]);
            acc[NH]   = fmaf(av, Wr[j * 6 + 4], acc[NH]);
            acc[NH+1] = fmaf(av, Wr[j * 6 + 5], acc[NH + 1]);
        }
#pragma unroll
        for (int j = 0; j < 32; ++j) a0[j] = a1[j];
    }
}

// per-lane x-row (128 k, contiguous) against W6 x-part; n -> slots 4,5
__device__ __forceinline__ void acc_xrow(const float4* __restrict__ xr,
                                         const float* __restrict__ W6k,
                                         float* __restrict__ acc)
{
    float4 c0[8], c1[8];
#pragma unroll
    for (int j = 0; j < 8; ++j) c0[j] = xr[j];
    for (int q = 0; q < 32; q += 8) {
        if (q + 8 < 32) {
#pragma unroll
            for (int j = 0; j < 8; ++j) c1[j] = xr[q + 8 + j];
        }
#pragma unroll
        for (int j = 0; j < 8; ++j) {
            const float* Wr = W6k + (size_t)((q + j) * 4) * 6;
            float e0 = c0[j].x, e1 = c0[j].y, e2 = c0[j].z, e3 = c0[j].w;
#pragma unroll
            for (int t2 = 0; t2 < 4; ++t2) {
                float av = (t2 == 0) ? e0 : (t2 == 1) ? e1 : (t2 == 2) ? e2 : e3;
                acc[0] = fmaf(av, Wr[t2 * 6 + 0], acc[0]);
                acc[1] = fmaf(av, Wr[t2 * 6 + 1], acc[1]);
                acc[2] = fmaf(av, Wr[t2 * 6 + 2], acc[2]);
                acc[3] = fmaf(av, Wr[t2 * 6 + 3], acc[3]);
                acc[4] = fmaf(av, Wr[t2 * 6 + 4], acc[4]);
                acc[5] = fmaf(av, Wr[t2 * 6 + 5], acc[5]);
            }
        }
#pragma unroll
        for (int j = 0; j < 8; ++j) c0[j] = c1[j];
    }
}

// ---------------------------------------------------------------------------
// prep kernels
// ---------------------------------------------------------------------------
__global__ __launch_bounds__(256)
void transpose_x(const float* __restrict__ x, float* __restrict__ xT)
{
    const int t = blockIdx.x >> 2;
    const int f0 = (blockIdx.x & 3) * 32;
    const int b = threadIdx.x;
#pragma unroll 4
    for (int ff = 0; ff < 32; ++ff) {
        int f = f0 + ff;
        xT[(size_t)t * (F_ * B_) + (size_t)f * B_ + b] =
            x[(size_t)b * (S_ * F_) + (size_t)t * F_ + f];
    }
}

__global__ __launch_bounds__(256)
void prep_w6(const float* __restrict__ Wih, const float* __restrict__ Whh,
             float* __restrict__ W6, const float* __restrict__ csrc,
             float* __restrict__ cdst, int cn)
{
    int id = blockIdx.x * 256 + threadIdx.x;
    if (csrc && id < cn) cdst[id] = csrc[id];
    if (id >= 256 * 640 * 6) return;
    int up = id / 3840;
    int rem = id - up * 3840;
    int k = rem / 6, g = rem - k * 6;
    int row = (g >> 1) * H_ + up * 2 + (g & 1);
    float val;
    if (k < F_) val = Wih[(size_t)row * F_ + k];
    else        val = Whh[(size_t)row * H_ + (k - F_)];
    W6[id] = val;
}

__global__ __launch_bounds__(256)
void prep_bias(const float* __restrict__ ebih, const float* __restrict__ ebhh,
               const float* __restrict__ dbih, const float* __restrict__ dbhh,
               float* __restrict__ bias4e, float* __restrict__ bias4d,
               float* __restrict__ h0T, int* __restrict__ eflags,
               int* __restrict__ dflags)
{
    int id = blockIdx.x * 256 + threadIdx.x;
    if (id < H_ * B_) h0T[id] = 0.f;
    if (id < 256) { eflags[id] = 0; dflags[id] = 0; }
    if (id < H_) {
        bias4e[id * 4 + 0] = ebih[id] + ebhh[id];
        bias4e[id * 4 + 1] = ebih[H_ + id] + ebhh[H_ + id];
        bias4e[id * 4 + 2] = ebih[2 * H_ + id];
        bias4e[id * 4 + 3] = ebhh[2 * H_ + id];
        bias4d[id * 4 + 0] = dbih[id] + dbhh[id];
        bias4d[id * 4 + 1] = dbih[H_ + id] + dbhh[H_ + id];
        bias4d[id * 4 + 2] = dbih[2 * H_ + id];
        bias4d[id * 4 + 3] = dbhh[2 * H_ + id];
    }
}

// ---------------------------------------------------------------------------
// PERSISTENT encoder (round-10 compute, packed flags + cheap poll)
// ---------------------------------------------------------------------------
__global__ __launch_bounds__(512)
void enc_persist(const float* __restrict__ xT,
                 const float* __restrict__ W6,
                 const float* __restrict__ bias4,
                 const float* __restrict__ h0T,
                 float* __restrict__ encT,
                 int* __restrict__ eflags)
{
    __shared__ float accL[4][64][6];
    const int tid = threadIdx.x;
    const int lane = tid & 63;
    const int w = tid >> 6;
    const int kw = w >> 2;
    const int uq = w & 3;
    const int bid = blockIdx.x;
    const int jb = bid & 63;
    const int bt = bid >> 6;
    const int gbase = bt * 64;
    const int b = bt * 64 + lane;
    const int up = jb * 4 + uq;
    const float* Wb = W6 + (size_t)up * 3840;
    const int u0 = up * 2, u1 = u0 + 1;
    const float4 bb0 = *(const float4*)(bias4 + u0 * 4);
    const float4 bb1 = *(const float4*)(bias4 + u1 * 4);

    for (int t = 0; t < S_; ++t) {
        const float* inT = xT + (size_t)t * (F_ * B_);
        const float* hin = (t == 0) ? h0T : encT + (size_t)(t - 1) * HSLICE;
        float* hout = encT + (size_t)t * HSLICE;

        float acc[8];
#pragma unroll
        for (int g = 0; g < 8; ++g) acc[g] = 0.f;

        if (kw == 0) acc_chunks<4>(inT, Wb, F_, b, acc);

        if (t > 0) group_wait(eflags, gbase, tid, t);
        __syncthreads();

        float hold0 = 0.f, hold1 = 0.f;
        if (kw == 0) {
            hold0 = hin[(size_t)u0 * B_ + b];
            hold1 = hin[(size_t)u1 * B_ + b];
            acc_chunks<6>(hin, Wb + F_ * 6, 192, b, acc);
        } else {
            acc_chunks<6>(hin + (size_t)192 * B_, Wb + 320 * 6, 320, b, acc);
        }

        if (kw == 1) {
            accL[uq][lane][0] = acc[0]; accL[uq][lane][1] = acc[1];
            accL[uq][lane][2] = acc[2]; accL[uq][lane][3] = acc[3];
            accL[uq][lane][4] = acc[6]; accL[uq][lane][5] = acc[7];
        }
        __syncthreads();
        if (kw == 0) {
            float rr0 = 1.f / (1.f + expf(-(acc[0] + accL[uq][lane][0] + bb0.x)));
            float rr1 = 1.f / (1.f + expf(-(acc[1] + accL[uq][lane][1] + bb1.x)));
            float zz0 = 1.f / (1.f + expf(-(acc[2] + accL[uq][lane][2] + bb0.y)));
            float zz1 = 1.f / (1.f + expf(-(acc[3] + accL[uq][lane][3] + bb1.y)));
            float hn0 = acc[6] + accL[uq][lane][4] + bb0.w;
            float hn1 = acc[7] + accL[uq][lane][5] + bb1.w;
            float nn0 = tanhf(acc[4] + bb0.z + rr0 * hn0);
            float nn1 = tanhf(acc[5] + bb1.z + rr1 * hn1);
            stf(&hout[(size_t)u0 * B_ + b], (1.f - zz0) * nn0 + zz0 * hold0);
            stf(&hout[(size_t)u1 * B_ + b], (1.f - zz1) * nn1 + zz1 * hold1);
        }
        asm volatile("s_waitcnt vmcnt(0)" ::: "memory");
        __syncthreads();
        if (tid == 0) sti(&eflags[bid], t + 1);
    }
}

// ---------------------------------------------------------------------------
// PERSISTENT decoder: ring of virgin h slices (cached reads), sc1 publishes,
// 3 phases/step with split h-wait, packed flags + cheap poll.
// Epochs: 3st+1 = h(st+1) published, 3st+2 = hw2, 3st+3 = pred.
// ---------------------------------------------------------------------------
__global__ __launch_bounds__(512)
void dec_persist(const float* __restrict__ x,       // [B][S][F]
                 const int*   __restrict__ y,       // [B][C]
                 const float* __restrict__ W6,      // [256][640][6]
                 const float* __restrict__ bias4,   // [512][4]
                 const float* __restrict__ w2,      // [A][H]
                 const float* __restrict__ v,       // [A]
                 const float* __restrict__ proj,    // [B][S][A]
                 float* __restrict__ ring,          // [128][H][B]; slice0 = h_init
                 float* __restrict__ hLast,         // [H][B]
                 float* __restrict__ hw2,           // [B][A]
                 int* __restrict__ predRing,        // [C][B]
                 float* __restrict__ nlogp, float* __restrict__ preds,
                 int* __restrict__ dflags)          // [256]
{
    __shared__ float accL[4][64][6];   // phase-1 reduce; reused by phase 2
    __shared__ float sh[512];
    __shared__ float sScore[S_], sProb[S_];

    const int tid = threadIdx.x;
    const int lane = tid & 63;
    const int w = tid >> 6;
    const int kw = w >> 2;
    const int uq = w & 3;
    const int bid = blockIdx.x;
    const int bt = bid >> 6;
    const int gbase = bt * 64;
    const int b = bt * 64 + lane;
    const int up = (bid & 63) * 4 + uq;
    const float* Wb = W6 + (size_t)up * 3840;
    const int u0 = up * 2, u1 = u0 + 1;
    const float4 bb0 = *(const float4*)(bias4 + u0 * 4);
    const float4 bb1 = *(const float4*)(bias4 + u1 * 4);
    const float4 v0r = *(const float4*)(v + lane * 8);
    const float4 v1r = *(const float4*)(v + lane * 8 + 4);
    // phase-2 constants
    const int aq2 = __builtin_amdgcn_readfirstlane(w & 3);
    const int kh2 = __builtin_amdgcn_readfirstlane(w >> 2);
    const int a0p = (bid & 63) * 8 + aq2 * 2;
    const float* w2r0 = w2 + (size_t)a0p * H_ + kh2 * 256;
    const float* w2r1 = w2r0 + H_;
    float* accF = (float*)accL;

    for (int st = 0; st < C_; ++st) {
        const float* hin = ring + (size_t)st * HSLICE;
        float* hout = (st < C_ - 1) ? ring + (size_t)(st + 1) * HSLICE : hLast;

        // ================ phase 1: GRU ================
        if (st > 0) { group_wait(dflags, gbase, tid, 3 * st - 2); }
        __syncthreads();
        {
            float acc[8];
#pragma unroll
            for (int g = 0; g < 8; ++g) acc[g] = 0.f;

            float hold0 = 0.f, hold1 = 0.f;
            if (kw == 0) {
                hold0 = hin[(size_t)u0 * B_ + b];
                hold1 = hin[(size_t)u1 * B_ + b];
                acc_chunks<6>(hin, Wb + F_ * 6, 192, b, acc);
            } else {
                acc_chunks<6>(hin + (size_t)192 * B_, Wb + 320 * 6, 320, b, acc);
            }

            if (st > 0) {
                group_wait(dflags, gbase, tid, 3 * st);   // pred(st-1) ready
                __syncthreads();
                if (kw == 0) {
                    int pb = __hip_atomic_load(&predRing[(st - 1) * B_ + b],
                                               __ATOMIC_RELAXED,
                                               __HIP_MEMORY_SCOPE_AGENT);
                    const float4* xr =
                        (const float4*)(x + ((size_t)b * S_ + pb) * F_);
                    acc_xrow(xr, Wb, acc);
                }
            }

            if (kw == 1) {
                accL[uq][lane][0] = acc[0]; accL[uq][lane][1] = acc[1];
                accL[uq][lane][2] = acc[2]; accL[uq][lane][3] = acc[3];
                accL[uq][lane][4] = acc[6]; accL[uq][lane][5] = acc[7];
            }
            __syncthreads();
            if (kw == 0) {
                float rr0 = 1.f / (1.f + expf(-(acc[0] + accL[uq][lane][0] + bb0.x)));
                float rr1 = 1.f / (1.f + expf(-(acc[1] + accL[uq][lane][1] + bb1.x)));
                float zz0 = 1.f / (1.f + expf(-(acc[2] + accL[uq][lane][2] + bb0.y)));
                float zz1 = 1.f / (1.f + expf(-(acc[3] + accL[uq][lane][3] + bb1.y)));
                float hn0 = acc[6] + accL[uq][lane][4] + bb0.w;
                float hn1 = acc[7] + accL[uq][lane][5] + bb1.w;
                float nn0 = tanhf(acc[4] + bb0.z + rr0 * hn0);
                float nn1 = tanhf(acc[5] + bb1.z + rr1 * hn1);
                stf(&hout[(size_t)u0 * B_ + b], (1.f - zz0) * nn0 + zz0 * hold0);
                stf(&hout[(size_t)u1 * B_ + b], (1.f - zz1) * nn1 + zz1 * hold1);
            }
            asm volatile("s_waitcnt vmcnt(0)" ::: "memory");
            __syncthreads();
            if (tid == 0) sti(&dflags[bid], 3 * st + 1);
        }

        // ================ phase 2: hw2 GEMM slice ================
        group_wait(dflags, gbase, tid, 3 * st + 1);
        __syncthreads();
        {
            // cached reads of hout: virgin slice, first touch after the wait
            const float* hsrc = hout + (size_t)(kh2 * 256) * B_;
            float s0 = 0.f, s1 = 0.f;
            float c0[32], c1[32];
#pragma unroll
            for (int j = 0; j < 32; ++j) c0[j] = hsrc[(size_t)j * B_ + b];
            for (int kc = 0; kc < 256; kc += 32) {
                if (kc + 32 < 256) {
#pragma unroll
                    for (int j = 0; j < 32; ++j)
                        c1[j] = hsrc[(size_t)(kc + 32 + j) * B_ + b];
                }
#pragma unroll
                for (int j = 0; j < 32; ++j) {
                    s0 = fmaf(c0[j], w2r0[kc + j], s0);
                    s1 = fmaf(c0[j], w2r1[kc + j], s1);
                }
#pragma unroll
                for (int j = 0; j < 32; ++j) c0[j] = c1[j];
            }
            if (kh2 == 1) {
                accF[(aq2 * 64 + lane) * 2 + 0] = s0;
                accF[(aq2 * 64 + lane) * 2 + 1] = s1;
            }
            __syncthreads();
            if (kh2 == 0) {
                float t0 = s0 + accF[(aq2 * 64 + lane) * 2 + 0];
                float t1 = s1 + accF[(aq2 * 64 + lane) * 2 + 1];
                stf(&hw2[(size_t)b * A_ + a0p + 0], t0);
                stf(&hw2[(size_t)b * A_ + a0p + 1], t1);
            }
            asm volatile("s_waitcnt vmcnt(0)" ::: "memory");
            __syncthreads();
            if (tid == 0) sti(&dflags[bid], 3 * st + 2);
        }

        // ================ phase 3: attention (block = batch bb) ================
        group_wait(dflags, gbase, tid, 3 * st + 2);
        __syncthreads();
        {
            const int bb = bid;
            // hw2 is REUSED each step -> must bypass possibly-stale L2: sc1 row
            sh[tid] = ldf_sc(&hw2[(size_t)bb * A_ + tid]);
            __syncthreads();

            const float* epb = proj + (size_t)bb * (S_ * A_);
            float4 q0 = *(const float4*)&sh[lane * 8];
            float4 q1 = *(const float4*)&sh[lane * 8 + 4];
            for (int si = 0; si < 16; ++si) {
                int ss = si * 8 + w;
                const float* row = epb + (size_t)ss * A_ + lane * 8;
                float4 p0 = *(const float4*)(row);
                float4 p1 = *(const float4*)(row + 4);
                float acc = fmaxf(p0.x + q0.x, 0.f) * v0r.x
                          + fmaxf(p0.y + q0.y, 0.f) * v0r.y
                          + fmaxf(p0.z + q0.z, 0.f) * v0r.z
                          + fmaxf(p0.w + q0.w, 0.f) * v0r.w
                          + fmaxf(p1.x + q1.x, 0.f) * v1r.x
                          + fmaxf(p1.y + q1.y, 0.f) * v1r.y
                          + fmaxf(p1.z + q1.z, 0.f) * v1r.z
                          + fmaxf(p1.w + q1.w, 0.f) * v1r.w;
#pragma unroll
                for (int off = 32; off; off >>= 1) acc += __shfl_down(acc, off);
                if (lane == 0) sScore[ss] = acc;
            }
            __syncthreads();

            if (tid < 64) {
                float s0v = sScore[tid], s1v = sScore[tid + 64];
                float m = fmaxf(s0v, s1v);
#pragma unroll
                for (int off = 32; off; off >>= 1) m = fmaxf(m, __shfl_xor(m, off));
                float e0 = expf(s0v - m), e1 = expf(s1v - m);
                float se = e0 + e1;
#pragma unroll
                for (int off = 32; off; off >>= 1) se += __shfl_xor(se, off);
                float p0 = e0 / se, p1 = e1 / se;
                sProb[tid] = p0; sProb[tid + 64] = p1;
                float pm = fmaxf(p0, p1);
#pragma unroll
                for (int off = 32; off; off >>= 1) pm = fmaxf(pm, __shfl_xor(pm, off));
                float t0 = expf(p0 - pm), t1 = expf(p1 - pm);
                float T = t0 + t1;
#pragma unroll
                for (int off = 32; off; off >>= 1) T += __shfl_xor(T, off);
                float bv = p0; int bi2 = tid;
                if (p1 > bv) { bv = p1; bi2 = tid + 64; }
#pragma unroll
                for (int off = 32; off; off >>= 1) {
                    float ov = __shfl_xor(bv, off);
                    int oi = __shfl_xor(bi2, off);
                    if (ov > bv || (ov == bv && oi < bi2)) { bv = ov; bi2 = oi; }
                }
                if (tid == 0) {
                    int yy = y[(size_t)bb * C_ + st];
                    float py = sProb[yy];
                    nlogp[(size_t)st * B_ + bb] = -(py - pm - logf(T));
                    preds[(size_t)bb * C_ + st] = (float)bi2;
                    sti(&predRing[st * B_ + bb], bi2);
                }
            }
            asm volatile("s_waitcnt vmcnt(0)" ::: "memory");
            __syncthreads();
            if (tid == 0) sti(&dflags[bid], 3 * st + 3);
        }
    }
}

// ---------------------------------------------------------------------------
// proj[b][s][a] = sum_j encT[s][j][b] * w1[a][j]  (sB padded: kills 32-way
// bank conflict on the sB write phase)
// ---------------------------------------------------------------------------
__global__ __launch_bounds__(256)
void proj_gemm(const float* __restrict__ encT, const float* __restrict__ w1,
               float* __restrict__ proj)
{
    __shared__ float sA[32][128];
    __shared__ float sB[32][132];   // +4 pad: write stride 132 spreads banks
    const int tid = threadIdx.x;
    const int s = blockIdx.z;
    const int b0 = blockIdx.y * 128;
    const int a0 = blockIdx.x * 128;
    const int tx = tid & 15, ty = tid >> 4;

    float acc[8][8];
#pragma unroll
    for (int i = 0; i < 8; ++i)
#pragma unroll
        for (int j = 0; j < 8; ++j) acc[i][j] = 0.f;

    const float* Abase = encT + (size_t)s * HSLICE + b0;
    for (int kc = 0; kc < H_; kc += 32) {
#pragma unroll
        for (int p = 0; p < 16; ++p) {
            int idx = tid + p * 256;
            int kj = idx >> 7, bbb = idx & 127;
            sA[kj][bbb] = Abase[(size_t)(kc + kj) * B_ + bbb];
        }
#pragma unroll
        for (int p = 0; p < 16; ++p) {
            int idx = tid + p * 256;
            int aa = idx >> 5, kj = idx & 31;
            sB[kj][aa] = w1[(size_t)(a0 + aa) * H_ + kc + kj];
        }
        __syncthreads();
#pragma unroll
        for (int kj = 0; kj < 32; ++kj) {
            float4 af0 = *(const float4*)&sA[kj][ty * 8];
            float4 af1 = *(const float4*)&sA[kj][ty * 8 + 4];
            float4 bf0 = *(const float4*)&sB[kj][tx * 8];
            float4 bf1 = *(const float4*)&sB[kj][tx * 8 + 4];
            float am[8] = {af0.x, af0.y, af0.z, af0.w, af1.x, af1.y, af1.z, af1.w};
            float bn[8] = {bf0.x, bf0.y, bf0.z, bf0.w, bf1.x, bf1.y, bf1.z, bf1.w};
#pragma unroll
            for (int i = 0; i < 8; ++i)
#pragma unroll
                for (int j = 0; j < 8; ++j)
                    acc[i][j] = fmaf(am[i], bn[j], acc[i][j]);
        }
        __syncthreads();
    }
#pragma unroll
    for (int i = 0; i < 8; ++i) {
        float* dst = proj + ((size_t)(b0 + ty * 8 + i) * S_ + s) * A_ + a0 + tx * 8;
        *(float4*)(dst) = make_float4(acc[i][0], acc[i][1], acc[i][2], acc[i][3]);
        *(float4*)(dst + 4) = make_float4(acc[i][4], acc[i][5], acc[i][6], acc[i][7]);
    }
}

__global__ void final_loss(const float* __restrict__ nlogp, float* __restrict__ out)
{
    __shared__ float part[C_];
    const int i = threadIdx.x; // 128
    float s = 0.f;
    for (int b = 0; b < B_; ++b) s += nlogp[(size_t)i * B_ + b];
    part[i] = s / (float)B_;
    __syncthreads();
    if (i == 0) {
        float t = 0.f;
        for (int k = 0; k < C_; ++k) t += part[k];
        out[0] = t / (float)B_ / (float)C_;
    }
}

extern "C" void kernel_launch(void* const* d_in, const int* in_sizes, int n_in,
                              void* d_out, int out_size, void* d_ws, size_t ws_size,
                              hipStream_t stream)
{
    (void)in_sizes; (void)n_in; (void)out_size; (void)ws_size;
    const float* x    = (const float*)d_in[0];
    const int*   y    = (const int*)d_in[1];
    const float* eWih = (const float*)d_in[2];
    const float* eWhh = (const float*)d_in[3];
    const float* ebih = (const float*)d_in[4];
    const float* ebhh = (const float*)d_in[5];
    const float* dWih = (const float*)d_in[6];
    const float* dWhh = (const float*)d_in[7];
    const float* dbih = (const float*)d_in[8];
    const float* dbhh = (const float*)d_in[9];
    const float* w1   = (const float*)d_in[10];
    const float* w2   = (const float*)d_in[11];
    const float* v    = (const float*)d_in[12];
    float* out = (float*)d_out;

    float* ws = (float*)d_ws;
    // Region A [0, 16,777,216): encT during encode; h-ring[128] during decode.
    float* encT    = ws;
    float* ring    = ws;
    float* encT127 = ws + (size_t)127 * HSLICE;
    // Region B [16,777,216, 33,554,432): proj. Pre-proj: xT, W6e, h0T.
    float* projB  = ws + 16777216;
    float* xT     = projB;                    // 4,194,304
    float* W6e    = projB + 4194304;          // 983,040
    float* h0T    = projB + 5177344;          // 131,072
    // Region C beyond 33,554,432:
    float* C0     = ws + 33554432;
    float* bias4e = C0;                       // 2048
    float* bias4d = C0 + 2048;                // 2048
    float* nlogp  = C0 + 4096;                // 32,768
    float* hLast  = C0 + 36864;               // 131,072
    float* hw2    = C0 + 167936;              // 131,072
    float* W6d    = C0 + 430080;              // 983,040
    int*   eflags   = (int*)(C0 + 1413120);   // 256 ints (packed)
    int*   dflags   = eflags + 256;           // 256 ints (packed)
    int*   predRing = dflags + 256;           // 32,768 ints

    // ---- prep ----
    prep_bias<<<dim3(512), 256, 0, stream>>>(ebih, ebhh, dbih, dbhh,
                                             bias4e, bias4d, h0T, eflags, dflags);
    transpose_x<<<dim3(512), 256, 0, stream>>>(x, xT);
    prep_w6<<<dim3(3840), 256, 0, stream>>>(eWih, eWhh, W6e,
                                            (const float*)nullptr,
                                            (float*)nullptr, 0);

    // ---- encoder: ONE persistent kernel ----
    {
        void* a[] = { (void*)&xT, (void*)&W6e, (void*)&bias4e, (void*)&h0T,
                      (void*)&encT, (void*)&eflags };
        hipLaunchCooperativeKernel((const void*)enc_persist,
                                   dim3(256), dim3(512), a, 0, stream);
    }

    // ---- proj (reads all encT) ----
    proj_gemm<<<dim3(4, 2, 128), 256, 0, stream>>>(encT, w1, projB);

    // ---- decoder prep: W6d (region C) + copy h_init -> ring[0] ----
    prep_w6<<<dim3(3840), 256, 0, stream>>>(dWih, dWhh, W6d,
                                            encT127, ring, HSLICE);

    // ---- decoder: ONE persistent kernel ----
    {
        void* a[] = { (void*)&x, (void*)&y, (void*)&W6d, (void*)&bias4d,
                      (void*)&w2, (void*)&v, (void*)&projB, (void*)&ring,
                      (void*)&hLast, (void*)&hw2, (void*)&predRing,
                      (void*)&nlogp, (void*)&out, (void*)&dflags };
        hipLaunchCooperativeKernel((const void*)dec_persist,
                                   dim3(256), dim3(512), a, 0, stream);
    }

    final_loss<<<dim3(1), 128, 0, stream>>>(nlogp, out + (size_t)B_ * C_);
}

// Round 14
// 7232.755 us; speedup vs baseline: 2.6905x; 2.1343x over previous
//
#include <hip/hip_runtime.h>
#include <math.h>

// Problem constants
#define B_ 256
#define S_ 128
#define F_ 128
#define H_ 512
#define A_ 512
#define C_ 128
#define HSLICE (H_ * B_)   // 131072 floats per h slice

#define DOT4(va, vb) ((va).x*(vb).x + (va).y*(vb).y + (va).z*(vb).z + (va).w*(vb).w)

// ---------------------------------------------------------------------------
// deep-prefetch k-major dot: 32-float double-buffer window.
// acc slots 0..3 = r0,r1,z0,z1 ; acc[NH],acc[NH+1] = n0,n1 partial.
// ---------------------------------------------------------------------------
template<int NH>
__device__ __forceinline__ void acc_chunks(const float* __restrict__ src,
                                           const float* __restrict__ W6k,
                                           int nk, int b, float* __restrict__ acc)
{
    float a0[32], a1[32];
#pragma unroll
    for (int j = 0; j < 32; ++j) a0[j] = src[(size_t)j * B_ + b];
    for (int kc = 0; kc < nk; kc += 32) {
        if (kc + 32 < nk) {
#pragma unroll
            for (int j = 0; j < 32; ++j)
                a1[j] = src[(size_t)(kc + 32 + j) * B_ + b];
        }
        const float* Wr = W6k + (size_t)kc * 6;
#pragma unroll
        for (int j = 0; j < 32; ++j) {
            float av = a0[j];
            acc[0]    = fmaf(av, Wr[j * 6 + 0], acc[0]);
            acc[1]    = fmaf(av, Wr[j * 6 + 1], acc[1]);
            acc[2]    = fmaf(av, Wr[j * 6 + 2], acc[2]);
            acc[3]    = fmaf(av, Wr[j * 6 + 3], acc[3]);
            acc[NH]   = fmaf(av, Wr[j * 6 + 4], acc[NH]);
            acc[NH+1] = fmaf(av, Wr[j * 6 + 5], acc[NH + 1]);
        }
#pragma unroll
        for (int j = 0; j < 32; ++j) a0[j] = a1[j];
    }
}

// per-lane x-row (128 contiguous floats) against W6 x-part; n -> slots 4,5
__device__ __forceinline__ void acc_xrow(const float4* __restrict__ xr,
                                         const float* __restrict__ W6k,
                                         float* __restrict__ acc)
{
    float4 c0[8], c1[8];
#pragma unroll
    for (int j = 0; j < 8; ++j) c0[j] = xr[j];
    for (int q = 0; q < 32; q += 8) {
        if (q + 8 < 32) {
#pragma unroll
            for (int j = 0; j < 8; ++j) c1[j] = xr[q + 8 + j];
        }
#pragma unroll
        for (int j = 0; j < 8; ++j) {
            const float* Wr = W6k + (size_t)((q + j) * 4) * 6;
            float e0 = c0[j].x, e1 = c0[j].y, e2 = c0[j].z, e3 = c0[j].w;
#pragma unroll
            for (int t2 = 0; t2 < 4; ++t2) {
                float av = (t2 == 0) ? e0 : (t2 == 1) ? e1 : (t2 == 2) ? e2 : e3;
                acc[0] = fmaf(av, Wr[t2 * 6 + 0], acc[0]);
                acc[1] = fmaf(av, Wr[t2 * 6 + 1], acc[1]);
                acc[2] = fmaf(av, Wr[t2 * 6 + 2], acc[2]);
                acc[3] = fmaf(av, Wr[t2 * 6 + 3], acc[3]);
                acc[4] = fmaf(av, Wr[t2 * 6 + 4], acc[4]);
                acc[5] = fmaf(av, Wr[t2 * 6 + 5], acc[5]);
            }
        }
#pragma unroll
        for (int j = 0; j < 8; ++j) c0[j] = c1[j];
    }
}

// ---------------------------------------------------------------------------
// prep_all: W6e pack + xT transpose + biases + h0T zero.  grid 3840 x 256.
// ---------------------------------------------------------------------------
__global__ __launch_bounds__(256)
void prep_all(const float* __restrict__ x,
              const float* __restrict__ eWih, const float* __restrict__ eWhh,
              const float* __restrict__ ebih, const float* __restrict__ ebhh,
              const float* __restrict__ dbih, const float* __restrict__ dbhh,
              float* __restrict__ xT, float* __restrict__ W6e,
              float* __restrict__ bias4e, float* __restrict__ bias4d,
              float* __restrict__ h0T)
{
    int id = blockIdx.x * 256 + threadIdx.x;   // < 983040
    // W6e[up][k][6]
    {
        int up = id / 3840;
        int rem = id - up * 3840;
        int k = rem / 6, g = rem - k * 6;
        int row = (g >> 1) * H_ + up * 2 + (g & 1);
        float val;
        if (k < F_) val = eWih[(size_t)row * F_ + k];
        else        val = eWhh[(size_t)row * H_ + (k - F_)];
        W6e[id] = val;
    }
    // xT[t][f][b] = x[b][t][f]  (4,194,304 elems)
#pragma unroll
    for (int r = 0; r < 5; ++r) {
        int xid = id + r * 983040;
        if (xid < S_ * F_ * B_) {
            int b2 = xid & 255, f = (xid >> 8) & 127, t = xid >> 15;
            xT[xid] = x[(size_t)b2 * (S_ * F_) + (size_t)t * F_ + f];
        }
    }
    if (id < H_ * B_) h0T[id] = 0.f;
    if (id < H_) {
        bias4e[id * 4 + 0] = ebih[id] + ebhh[id];
        bias4e[id * 4 + 1] = ebih[H_ + id] + ebhh[H_ + id];
        bias4e[id * 4 + 2] = ebih[2 * H_ + id];
        bias4e[id * 4 + 3] = ebhh[2 * H_ + id];
        bias4d[id * 4 + 0] = dbih[id] + dbhh[id];
        bias4d[id * 4 + 1] = dbih[H_ + id] + dbhh[H_ + id];
        bias4d[id * 4 + 2] = dbih[2 * H_ + id];
        bias4d[id * 4 + 3] = dbhh[2 * H_ + id];
    }
}

// prep_dec: W6d pack + w2q pack.  grid 3840 x 256.
__global__ __launch_bounds__(256)
void prep_dec(const float* __restrict__ dWih, const float* __restrict__ dWhh,
              const float* __restrict__ w2,
              float* __restrict__ W6d, float4* __restrict__ w2q)
{
    int id = blockIdx.x * 256 + threadIdx.x;
    {
        int up = id / 3840;
        int rem = id - up * 3840;
        int k = rem / 6, g = rem - k * 6;
        int row = (g >> 1) * H_ + up * 2 + (g & 1);
        float val;
        if (k < F_) val = dWih[(size_t)row * F_ + k];
        else        val = dWhh[(size_t)row * H_ + (k - F_)];
        W6d[id] = val;
    }
    if (id < 128 * 512) {
        int k4 = id >> 9, a = id & 511;
        const float* s = w2 + (size_t)a * H_ + k4 * 4;
        w2q[id] = make_float4(s[0], s[1], s[2], s[3]);
    }
}

// ---------------------------------------------------------------------------
// GRU step: grid 1024 = up(256) x bh(4); 128 threads = 2 waves (kw).
// Block owns unit-pair `up` x 64 batches. x-part: either k-major inT
// (encoder) or per-lane x-row gather via pred (decoder, st>0).
// ---------------------------------------------------------------------------
__global__ __launch_bounds__(128)
void gru_step(const float* __restrict__ inT,    // [F][B] k-major or nullptr
              const float* __restrict__ x,      // [B][S][F] or nullptr
              const int*   __restrict__ pred,   // [B] or nullptr
              const float* __restrict__ hinT,   // [H][B]
              const float* __restrict__ W6,     // [256][640][6]
              const float* __restrict__ bias4,  // [512][4]
              float* __restrict__ houtT,        // [H][B]
              float* __restrict__ hB)           // [B][H] or nullptr
{
    __shared__ float accL[64][6];
    const int tid = threadIdx.x;
    const int lane = tid & 63;
    const int kw = tid >> 6;
    const int up = blockIdx.x & 255;
    const int bh = blockIdx.x >> 8;
    const int b = bh * 64 + lane;
    const float* Wb = W6 + (size_t)up * 3840;
    const int u0 = up * 2, u1 = u0 + 1;

    float acc[8];
#pragma unroll
    for (int g = 0; g < 8; ++g) acc[g] = 0.f;

    float hold0 = 0.f, hold1 = 0.f;
    if (kw == 0) {
        hold0 = hinT[(size_t)u0 * B_ + b];
        hold1 = hinT[(size_t)u1 * B_ + b];
        if (inT) {
            acc_chunks<4>(inT, Wb, F_, b, acc);
        } else if (pred) {
            int pb = pred[b];
            const float4* xr = (const float4*)(x + ((size_t)b * S_ + pb) * F_);
            acc_xrow(xr, Wb, acc);
        }
        acc_chunks<6>(hinT, Wb + F_ * 6, 192, b, acc);
    } else {
        acc_chunks<6>(hinT + (size_t)192 * B_, Wb + 320 * 6, 320, b, acc);
    }

    if (kw == 1) {
        accL[lane][0] = acc[0]; accL[lane][1] = acc[1];
        accL[lane][2] = acc[2]; accL[lane][3] = acc[3];
        accL[lane][4] = acc[6]; accL[lane][5] = acc[7];
    }
    __syncthreads();
    if (kw == 0) {
        const float4 bb0 = *(const float4*)(bias4 + u0 * 4);
        const float4 bb1 = *(const float4*)(bias4 + u1 * 4);
        float rr0 = 1.f / (1.f + expf(-(acc[0] + accL[lane][0] + bb0.x)));
        float rr1 = 1.f / (1.f + expf(-(acc[1] + accL[lane][1] + bb1.x)));
        float zz0 = 1.f / (1.f + expf(-(acc[2] + accL[lane][2] + bb0.y)));
        float zz1 = 1.f / (1.f + expf(-(acc[3] + accL[lane][3] + bb1.y)));
        float hn0 = acc[6] + accL[lane][4] + bb0.w;
        float hn1 = acc[7] + accL[lane][5] + bb1.w;
        float nn0 = tanhf(acc[4] + bb0.z + rr0 * hn0);
        float nn1 = tanhf(acc[5] + bb1.z + rr1 * hn1);
        float h0v = (1.f - zz0) * nn0 + zz0 * hold0;
        float h1v = (1.f - zz1) * nn1 + zz1 * hold1;
        houtT[(size_t)u0 * B_ + b] = h0v;
        houtT[(size_t)u1 * B_ + b] = h1v;
        if (hB) {
            hB[(size_t)b * H_ + u0] = h0v;
            hB[(size_t)b * H_ + u1] = h1v;
        }
    }
}

// ---------------------------------------------------------------------------
// Fused w2 + attention + softmax + argmax + loss + pred publish.
// Block = batch b, 512 threads (8 waves).
// ---------------------------------------------------------------------------
__global__ __launch_bounds__(512)
void w2attn_step(const float* __restrict__ hB,    // [B][H]
                 const float4* __restrict__ w2q,  // [128 k4][512 a]
                 const float* __restrict__ v, const int* __restrict__ y,
                 int step, const float* __restrict__ proj,  // [b][s][a]
                 int* __restrict__ predBuf,
                 float* __restrict__ nlogp, float* __restrict__ preds_out)
{
    const int b = blockIdx.x;
    const int tid = threadIdx.x;
    __shared__ float sh[512];
    __shared__ float sq[512];
    __shared__ float sScore[S_], sProb[S_];

    sh[tid] = hB[(size_t)b * H_ + tid];
    __syncthreads();

    // ---- hw2[b][a], a = tid ----
    {
        float acc = 0.f;
        const float4* wp = w2q + tid;
#pragma unroll 8
        for (int k4 = 0; k4 < 128; ++k4) {
            float4 hv = *(const float4*)&sh[k4 * 4];
            float4 wv4 = wp[(size_t)k4 * 512];
            acc += DOT4(hv, wv4);
        }
        sq[tid] = acc;
    }
    __syncthreads();

    // ---- scores: wave wv handles s = si*8+wv; lane owns 8-wide A slice ----
    const int wv = tid >> 6, ln = tid & 63;
    float4 q0 = *(const float4*)&sq[ln * 8];
    float4 q1 = *(const float4*)&sq[ln * 8 + 4];
    float4 v0r = *(const float4*)(v + ln * 8);
    float4 v1r = *(const float4*)(v + ln * 8 + 4);
    const float* epb = proj + (size_t)b * (S_ * A_);
    for (int si = 0; si < 16; ++si) {
        int s = si * 8 + wv;
        const float* row = epb + (size_t)s * A_ + ln * 8;
        float4 p0 = *(const float4*)(row);
        float4 p1 = *(const float4*)(row + 4);
        float acc = fmaxf(p0.x + q0.x, 0.f) * v0r.x
                  + fmaxf(p0.y + q0.y, 0.f) * v0r.y
                  + fmaxf(p0.z + q0.z, 0.f) * v0r.z
                  + fmaxf(p0.w + q0.w, 0.f) * v0r.w
                  + fmaxf(p1.x + q1.x, 0.f) * v1r.x
                  + fmaxf(p1.y + q1.y, 0.f) * v1r.y
                  + fmaxf(p1.z + q1.z, 0.f) * v1r.z
                  + fmaxf(p1.w + q1.w, 0.f) * v1r.w;
#pragma unroll
        for (int off = 32; off; off >>= 1) acc += __shfl_down(acc, off);
        if (ln == 0) sScore[s] = acc;
    }
    __syncthreads();

    // ---- softmax / log_softmax / argmax / loss (one wave) ----
    if (tid < 64) {
        float s0v = sScore[tid], s1v = sScore[tid + 64];
        float m = fmaxf(s0v, s1v);
#pragma unroll
        for (int off = 32; off; off >>= 1) m = fmaxf(m, __shfl_xor(m, off));
        float e0 = expf(s0v - m), e1 = expf(s1v - m);
        float se = e0 + e1;
#pragma unroll
        for (int off = 32; off; off >>= 1) se += __shfl_xor(se, off);
        float p0 = e0 / se, p1 = e1 / se;
        sProb[tid] = p0; sProb[tid + 64] = p1;
        float pm = fmaxf(p0, p1);
#pragma unroll
        for (int off = 32; off; off >>= 1) pm = fmaxf(pm, __shfl_xor(pm, off));
        float t0 = expf(p0 - pm), t1 = expf(p1 - pm);
        float T = t0 + t1;
#pragma unroll
        for (int off = 32; off; off >>= 1) T += __shfl_xor(T, off);
        float bv = p0; int bi2 = tid;
        if (p1 > bv) { bv = p1; bi2 = tid + 64; }
#pragma unroll
        for (int off = 32; off; off >>= 1) {
            float ov = __shfl_xor(bv, off);
            int oi = __shfl_xor(bi2, off);
            if (ov > bv || (ov == bv && oi < bi2)) { bv = ov; bi2 = oi; }
        }
        if (tid == 0) {
            int yy = y[(size_t)b * C_ + step];
            float py = sProb[yy];
            nlogp[(size_t)step * B_ + b] = -(py - pm - logf(T));
            preds_out[(size_t)b * C_ + step] = (float)bi2;
            predBuf[b] = bi2;
        }
    }
}

// ---------------------------------------------------------------------------
// proj[b][s][a] = sum_j encT[s][j][b] * w1[a][j]   (padded sB: no 32-way
// bank conflicts on the write phase)
// ---------------------------------------------------------------------------
__global__ __launch_bounds__(256)
void proj_gemm(const float* __restrict__ encT, const float* __restrict__ w1,
               float* __restrict__ proj)
{
    __shared__ float sA[32][128];
    __shared__ float sB[32][132];
    const int tid = threadIdx.x;
    const int s = blockIdx.z;
    const int b0 = blockIdx.y * 128;
    const int a0 = blockIdx.x * 128;
    const int tx = tid & 15, ty = tid >> 4;

    float acc[8][8];
#pragma unroll
    for (int i = 0; i < 8; ++i)
#pragma unroll
        for (int j = 0; j < 8; ++j) acc[i][j] = 0.f;

    const float* Abase = encT + (size_t)s * HSLICE + b0;
    for (int kc = 0; kc < H_; kc += 32) {
#pragma unroll
        for (int p = 0; p < 16; ++p) {
            int idx = tid + p * 256;
            int kj = idx >> 7, bbb = idx & 127;
            sA[kj][bbb] = Abase[(size_t)(kc + kj) * B_ + bbb];
        }
#pragma unroll
        for (int p = 0; p < 16; ++p) {
            int idx = tid + p * 256;
            int aa = idx >> 5, kj = idx & 31;
            sB[kj][aa] = w1[(size_t)(a0 + aa) * H_ + kc + kj];
        }
        __syncthreads();
#pragma unroll
        for (int kj = 0; kj < 32; ++kj) {
            float4 af0 = *(const float4*)&sA[kj][ty * 8];
            float4 af1 = *(const float4*)&sA[kj][ty * 8 + 4];
            float4 bf0 = *(const float4*)&sB[kj][tx * 8];
            float4 bf1 = *(const float4*)&sB[kj][tx * 8 + 4];
            float am[8] = {af0.x, af0.y, af0.z, af0.w, af1.x, af1.y, af1.z, af1.w};
            float bn[8] = {bf0.x, bf0.y, bf0.z, bf0.w, bf1.x, bf1.y, bf1.z, bf1.w};
#pragma unroll
            for (int i = 0; i < 8; ++i)
#pragma unroll
                for (int j = 0; j < 8; ++j)
                    acc[i][j] = fmaf(am[i], bn[j], acc[i][j]);
        }
        __syncthreads();
    }
#pragma unroll
    for (int i = 0; i < 8; ++i) {
        float* dst = proj + ((size_t)(b0 + ty * 8 + i) * S_ + s) * A_ + a0 + tx * 8;
        *(float4*)(dst) = make_float4(acc[i][0], acc[i][1], acc[i][2], acc[i][3]);
        *(float4*)(dst + 4) = make_float4(acc[i][4], acc[i][5], acc[i][6], acc[i][7]);
    }
}

__global__ void final_loss(const float* __restrict__ nlogp, float* __restrict__ out)
{
    __shared__ float part[C_];
    const int i = threadIdx.x; // 128
    float s = 0.f;
    for (int b = 0; b < B_; ++b) s += nlogp[(size_t)i * B_ + b];
    part[i] = s / (float)B_;
    __syncthreads();
    if (i == 0) {
        float t = 0.f;
        for (int k = 0; k < C_; ++k) t += part[k];
        out[0] = t / (float)B_ / (float)C_;
    }
}

extern "C" void kernel_launch(void* const* d_in, const int* in_sizes, int n_in,
                              void* d_out, int out_size, void* d_ws, size_t ws_size,
                              hipStream_t stream)
{
    (void)in_sizes; (void)n_in; (void)out_size; (void)ws_size;
    const float* x    = (const float*)d_in[0];
    const int*   y    = (const int*)d_in[1];
    const float* eWih = (const float*)d_in[2];
    const float* eWhh = (const float*)d_in[3];
    const float* ebih = (const float*)d_in[4];
    const float* ebhh = (const float*)d_in[5];
    const float* dWih = (const float*)d_in[6];
    const float* dWhh = (const float*)d_in[7];
    const float* dbih = (const float*)d_in[8];
    const float* dbhh = (const float*)d_in[9];
    const float* w1   = (const float*)d_in[10];
    const float* w2   = (const float*)d_in[11];
    const float* v    = (const float*)d_in[12];
    float* out = (float*)d_out;

    float* ws = (float*)d_ws;
    // Region A [0, 16,777,216): encT (slice 127 stays live through decode).
    float* encT    = ws;
    float* encT127 = ws + (size_t)127 * HSLICE;
    // Region B [16,777,216, 33,554,432): proj. Pre-proj: xT, W6e, h0T.
    float* projB  = ws + 16777216;
    float* xT     = projB;                    // 4,194,304
    float* W6e    = projB + 4194304;          // 983,040
    float* h0T    = projB + 5177344;          // 131,072
    // Region C beyond 33,554,432:
    float* C0     = ws + 33554432;
    float* bias4e = C0;                       // 2048
    float* bias4d = C0 + 2048;                // 2048
    float* nlogp  = C0 + 4096;                // 32,768
    float* hT0    = C0 + 36864;               // 131,072
    float* hT1    = C0 + 167936;              // 131,072
    float* hB     = C0 + 299008;              // 131,072
    float* w2qf   = C0 + 430080;              // 262,144
    float* W6d    = C0 + 692224;              // 983,040
    int*   predBuf = (int*)(C0 + 1675264);    // 256 ints

    // ---- prep (1 launch) ----
    prep_all<<<dim3(3840), 256, 0, stream>>>(x, eWih, eWhh, ebih, ebhh,
                                             dbih, dbhh, xT, W6e,
                                             bias4e, bias4d, h0T);

    // ---- encoder: 128 launched steps ----
    for (int t = 0; t < S_; ++t) {
        const float* hin = (t == 0) ? h0T : encT + (size_t)(t - 1) * HSLICE;
        gru_step<<<dim3(1024), 128, 0, stream>>>(
            xT + (size_t)t * (F_ * B_), nullptr, nullptr,
            hin, W6e, bias4e, encT + (size_t)t * HSLICE, nullptr);
    }

    // ---- proj ----
    proj_gemm<<<dim3(4, 2, 128), 256, 0, stream>>>(encT, w1, projB);

    // ---- decoder prep (1 launch) ----
    prep_dec<<<dim3(3840), 256, 0, stream>>>(dWih, dWhh, w2, W6d, (float4*)w2qf);

    // ---- decoder: 128 x 2 launched steps ----
    float* hb[2] = { hT0, hT1 };
    for (int st = 0; st < C_; ++st) {
        const float* hin = (st == 0) ? encT127 : hb[(st & 1) ^ 1];
        float* hout = hb[st & 1];
        gru_step<<<dim3(1024), 128, 0, stream>>>(
            nullptr, x, (st > 0) ? predBuf : nullptr,
            hin, W6d, bias4d, hout, hB);
        w2attn_step<<<dim3(256), 512, 0, stream>>>(
            hB, (const float4*)w2qf, v, y, st, projB, predBuf, nlogp, out);
    }

    final_loss<<<dim3(1), 128, 0, stream>>>(nlogp, out + (size_t)B_ * C_);
}